// Round 8
// baseline (1994.125 us; speedup 1.0000x reference)
//
#include <hip/hip_runtime.h>
#include <hip/hip_bf16.h>

typedef __attribute__((ext_vector_type(4))) float f32x4;
typedef __attribute__((ext_vector_type(8))) short s16x8;
typedef __attribute__((ext_vector_type(4))) short s16x4;
typedef __attribute__((ext_vector_type(8))) unsigned short u16x8;
typedef __attribute__((ext_vector_type(4))) unsigned short u16x4;
typedef __attribute__((ext_vector_type(4))) float fv4;

#define DEV static __device__ __forceinline__

DEV unsigned short f2bf(float f) {
  union { float f; unsigned u; } v; v.f = f;
  return (unsigned short)((v.u + 0x7fffu + ((v.u >> 16) & 1u)) >> 16);
}
DEV float bf2f(unsigned short u) {
  union { unsigned u; float f; } v; v.u = ((unsigned)u) << 16; return v.f;
}

typedef const __attribute__((address_space(1))) void* gas_t;
typedef __attribute__((address_space(3))) void* las_t;
DEV void load_lds16(const void* g, void* l) {
  __builtin_amdgcn_global_load_lds((gas_t)g, (las_t)l, 16, 0, 0);
}

// ---------------- fp32 -> bf16 convert ----------------
__global__ __launch_bounds__(256) void cvt_kernel(const float* __restrict__ in,
                                                  unsigned short* __restrict__ out,
                                                  int n4) {
  int i = blockIdx.x * 256 + threadIdx.x;
  int stride = gridDim.x * 256;
  for (; i < n4; i += stride) {
    fv4 v = *(const fv4*)(in + (size_t)i * 4);
    u16x4 o;
    o[0] = f2bf(v[0]); o[1] = f2bf(v[1]); o[2] = f2bf(v[2]); o[3] = f2bf(v[3]);
    *(u16x4*)(out + (size_t)i * 4) = o;
  }
}

// ------- 128x256 BT GEMM, BK=32, ring-3 LDS, BARRIER-FREE flag handshake ---
// C[m,n] = sum_k A[m,k]*B[n,k].  M mult of 128, N mult of 256, K mult of 32.
// R8 thesis (from R7 counters, corrected MFMA cost = 4.85 cy/CU-wide):
// per-iter wall 2568 cy = MFMA 1242 + ~1300 of LDS+vmcnt+barrier SERIAL time,
// because the per-tile s_barrier re-syncs all waves: read-burst then
// MFMA-burst, pipes never overlap (5 structures, all 44-49% MfmaUtil).
// Fix: NO barrier in the K-loop. Per-wave LDS flags:
//   sc[w] = my staging committed through tile sc   (write after counted vmcnt)
//   rc[w] = my frag-reads done through tile rc     (write after lgkmcnt(0))
// Iter t: poll rc[*]>=t-1 ; stage t+2 ; vmcnt(6) ; sc=t+1 ; poll sc[*]>=t ;
//         read frags(t) ; rc=t ; 32 MFMA.  Waves drift freely ~1 tile ->
// one wave's ds_reads run under another's MFMA.
// Swizzle (verified 0 conflicts): byte ^= ((row>>1)&3)<<4 on both sides.
// EPI: 0 = bf16 out (ldc=N), 1 = +bias[n] bf16, 2 = Vt mapping
template<int EPI>
__global__ __launch_bounds__(256, 2) void gemm128(const unsigned short* __restrict__ A,
                                                  const unsigned short* __restrict__ B,
                                                  unsigned short* __restrict__ C,
                                                  const float* __restrict__ bias,
                                                  int N, int K, int bxsh) {
  __shared__ unsigned short lds[3][12288]; // slot: A[128*32] then B[256*32] = 24 KiB
  __shared__ int flags[8];                 // [0..3]=sc per wave, [4..7]=rc per wave
  volatile int* vfl = flags;

  const int t = threadIdx.x;
  const int lane = t & 63;
  const int w = t >> 6;     // 0..3
  const int wr = w >> 1;    // A 64-row half
  const int wc = w & 1;     // B 128-col half
  const int r0 = lane & 15;
  const int g = lane >> 4;  // 0..3

  const int bid = blockIdx.x;
  const int bx = bid & ((1 << bxsh) - 1);
  const int by = bid >> bxsh;
  const long brow = (long)by * 128;
  const long bcol = (long)bx * 256;

  const int srow = t >> 2;  // 0..63
  const int scol = ((t & 3) ^ ((t >> 3) & 3)) * 8;
  const unsigned short* As = A + (brow + srow) * (long)K + scol;
  const unsigned short* Bs = B + (bcol + srow) * (long)K + scol;
  const int dst = t * 8;

#define STG(sl, kt)                                                  \
  do {                                                               \
    const long c0_ = (long)(kt) << 5;                                \
    load_lds16(As + c0_,                   &lds[sl][dst]);           \
    load_lds16(As + 64 * (long)K + c0_,    &lds[sl][2048 + dst]);    \
    load_lds16(Bs + c0_,                   &lds[sl][4096 + dst]);    \
    load_lds16(Bs + 64 * (long)K + c0_,    &lds[sl][6144 + dst]);    \
    load_lds16(Bs + 128 * (long)K + c0_,   &lds[sl][8192 + dst]);    \
    load_lds16(Bs + 192 * (long)K + c0_,   &lds[sl][10240 + dst]);   \
  } while (0)

#define POLL_GE(base, target)                                        \
  do {                                                               \
    for (;;) {                                                       \
      int m0_ = vfl[(base) + 0]; int m1_ = vfl[(base) + 1];          \
      int m2_ = vfl[(base) + 2]; int m3_ = vfl[(base) + 3];          \
      int mm_ = min(min(m0_, m1_), min(m2_, m3_));                   \
      if (mm_ >= (target)) break;                                    \
      __builtin_amdgcn_s_sleep(1);                                   \
    }                                                                \
    asm volatile("" ::: "memory");                                   \
  } while (0)

  f32x4 acc[4][8] = {};
  const int NT = K >> 5;

  const int cswz = (g ^ ((r0 >> 1) & 3)) * 8;
  const int arow = wr * 64 + r0;
  const int brw = wc * 128 + r0;

  // init flags, stage tiles 0,1; commit tile 0; one startup barrier
  if (lane == 0) { vfl[w] = -1; vfl[4 + w] = -1; }
  STG(0, 0);
  STG(1, 1);
  asm volatile("s_waitcnt vmcnt(6)" ::: "memory");
  if (lane == 0) vfl[w] = 0;   // my tile-0 staging committed
  __syncthreads();

  int sl = 0;
  for (int kt = 0; kt < NT; ++kt) {
    // 1) slot for kt+2 reuses tile kt-1's slot: wait until everyone read it
    POLL_GE(4, kt - 1);
    int sl2 = sl + 2; if (sl2 >= 3) sl2 -= 3;
    if (kt + 2 < NT) {
      STG(sl2, kt + 2);
      asm volatile("s_waitcnt vmcnt(6)" ::: "memory");  // tile kt+1 committed
      if (lane == 0) vfl[w] = kt + 1;
    } else if (kt == NT - 2) {
      asm volatile("s_waitcnt vmcnt(0)" ::: "memory");  // tile NT-1 committed
      if (lane == 0) vfl[w] = NT - 1;
    }
    // 2) tile kt fully staged by all waves?
    POLL_GE(0, kt);
    // 3) frag reads
    const unsigned short* Lp = &lds[sl][0];
    s16x8 AF[4], BF[8];
#pragma unroll
    for (int m = 0; m < 4; ++m)
      AF[m] = *(const s16x8*)&Lp[(arow + m * 16) * 32 + cswz];
#pragma unroll
    for (int n = 0; n < 8; ++n)
      BF[n] = *(const s16x8*)&Lp[4096 + (brw + n * 16) * 32 + cswz];
    asm volatile("s_waitcnt lgkmcnt(0)" ::: "memory");
    __builtin_amdgcn_sched_barrier(0);
    if (lane == 0) vfl[4 + w] = kt;   // my reads of tile kt done
    // 4) MFMA
    __builtin_amdgcn_s_setprio(1);
#pragma unroll
    for (int m = 0; m < 4; ++m)
#pragma unroll
      for (int n = 0; n < 8; ++n)
        acc[m][n] = __builtin_amdgcn_mfma_f32_16x16x32_bf16(AF[m], BF[n], acc[m][n], 0, 0, 0);
    __builtin_amdgcn_s_setprio(0);
    __builtin_amdgcn_sched_barrier(0);
    sl = (sl == 2) ? 0 : sl + 1;
  }
#undef POLL_GE
#undef STG

  const int g4 = g * 4;
#pragma unroll
  for (int m = 0; m < 4; ++m) {
#pragma unroll
    for (int n = 0; n < 8; ++n) {
      f32x4 v = acc[m][n];
      long col = bcol + wc * 128 + n * 16 + r0;
#pragma unroll
      for (int r = 0; r < 4; ++r) {
        long row = brow + wr * 64 + m * 16 + g4 + r;
        float val = v[r];
        if (EPI == 1) val += bias[col];
        if (EPI == 2) {
          long addr = ((col >> 9) << 21) + (row << 9) + (col & 511);
          C[addr] = f2bf(val);
        } else {
          C[row * (long)N + col] = f2bf(val);
        }
      }
    }
  }
}

// ---------------- fused attention ----------------
// grid: 1024 = B(16) * NH(16) * 4 q-tiles ; block: 512 (8 waves x 16 q-rows)
__global__ __launch_bounds__(512, 2) void attn_kernel(const unsigned short* __restrict__ Q,
                                                      const unsigned short* __restrict__ K,
                                                      const unsigned short* __restrict__ V,
                                                      const unsigned short* __restrict__ EP,
                                                      float* __restrict__ out) {
  __shared__ unsigned short lds[256 * 136]; // also used as [128][264]
  const int t = threadIdx.x;
  const int lane = t & 63;
  const int w = t >> 6;
  const int bid = blockIdx.x;
  const int qt = bid & 3;
  const int h = (bid >> 2) & 15;
  const int b = bid >> 6;
  const int r0 = lane & 15;
  const int g = lane >> 4;

  const int qrow = qt * 128 + w * 16;

  s16x8 qf[8];
  {
    const unsigned short* qp = Q + ((size_t)(b * 512 + qrow + r0)) * 4096 + h * 256 + g * 8;
#pragma unroll
    for (int s = 0; s < 8; ++s) qf[s] = *(const s16x8*)(qp + s * 32);
  }

  f32x4 st[32];
#pragma unroll
  for (int f = 0; f < 32; ++f) st[f] = f32x4{0.f, 0.f, 0.f, 0.f};

#pragma unroll
  for (int kc = 0; kc < 4; ++kc) {
    {
      const unsigned short* kp = K + ((size_t)(b * 512 + kc * 128)) * 4096 + h * 256;
#pragma unroll
      for (int u = 0; u < 8; ++u) {
        int fidx = u * 4096 + t * 8;
        int row = fidx >> 8, c = fidx & 255;
        u16x8 v = *(const u16x8*)(kp + (size_t)row * 4096 + c);
        *(u16x8*)&lds[row * 264 + c] = v;
      }
    }
    __syncthreads();
#pragma unroll
    for (int mf = 0; mf < 8; ++mf) {
      const unsigned short* lk = &lds[(mf * 16 + r0) * 264 + g * 8];
#pragma unroll
      for (int s = 0; s < 8; ++s) {
        s16x8 af = *(const s16x8*)(lk + s * 32);
        st[kc * 8 + mf] = __builtin_amdgcn_mfma_f32_16x16x32_bf16(af, qf[s], st[kc * 8 + mf], 0, 0, 0);
      }
    }
    __syncthreads();
  }

  {
    const unsigned short* ep = EP + ((size_t)(b * 512 + qrow + r0)) * 8192 + h * 512 + g * 4;
#pragma unroll
    for (int f = 0; f < 32; ++f) {
      u16x4 e = *(const u16x4*)(ep + f * 16);
#pragma unroll
      for (int r = 0; r < 4; ++r)
        st[f][r] = st[f][r] * 0.0625f + bf2f(e[r]);
    }
  }

  float mx = -1e30f;
#pragma unroll
  for (int f = 0; f < 32; ++f)
    mx = fmaxf(mx, fmaxf(fmaxf(st[f][0], st[f][1]), fmaxf(st[f][2], st[f][3])));
  mx = fmaxf(mx, __shfl_xor(mx, 16, 64));
  mx = fmaxf(mx, __shfl_xor(mx, 32, 64));
  float sum = 0.f;
#pragma unroll
  for (int f = 0; f < 32; ++f) {
#pragma unroll
    for (int r = 0; r < 4; ++r) {
      float e = __expf(st[f][r] - mx);
      st[f][r] = e;
      sum += e;
    }
  }
  sum += __shfl_xor(sum, 16, 64);
  sum += __shfl_xor(sum, 32, 64);
  const float rinv = 1.0f / sum;

  s16x8 pb[16];
#pragma unroll
  for (int p = 0; p < 16; ++p) {
    s16x8 v;
#pragma unroll
    for (int j = 0; j < 4; ++j) {
      v[j] = (short)f2bf(st[2 * p][j] * rinv);
      v[j + 4] = (short)f2bf(st[2 * p + 1][j] * rinv);
    }
    pb[p] = v;
  }

  f32x4 acc2[16];
#pragma unroll
  for (int d = 0; d < 16; ++d) acc2[d] = f32x4{0.f, 0.f, 0.f, 0.f};

#pragma unroll
  for (int kc = 0; kc < 4; ++kc) {
    {
      const unsigned short* vp = V + ((size_t)(b * 16 + h)) * 131072 + kc * 128;
#pragma unroll
      for (int u = 0; u < 8; ++u) {
        int fidx = u * 4096 + t * 8;
        int row = fidx >> 7, c = fidx & 127;
        u16x8 vv = *(const u16x8*)(vp + (size_t)row * 512 + c);
        *(u16x8*)&lds[row * 136 + c] = vv;
      }
    }
    __syncthreads();
#pragma unroll
    for (int d = 0; d < 16; ++d) {
      const unsigned short* lv = &lds[(d * 16 + r0) * 136 + g * 4];
#pragma unroll
      for (int p = 0; p < 4; ++p) {
        s16x4 a0 = *(const s16x4*)(lv + p * 32);
        s16x4 a1 = *(const s16x4*)(lv + p * 32 + 16);
        s16x8 av;
        av[0] = a0[0]; av[1] = a0[1]; av[2] = a0[2]; av[3] = a0[3];
        av[4] = a1[0]; av[5] = a1[1]; av[6] = a1[2]; av[7] = a1[3];
        acc2[d] = __builtin_amdgcn_mfma_f32_16x16x32_bf16(av, pb[kc * 4 + p], acc2[d], 0, 0, 0);
      }
    }
    __syncthreads();
  }

  {
    float* op = out + ((size_t)(b * 512 + qrow + r0)) * 4096 + h * 256 + g * 4;
#pragma unroll
    for (int d = 0; d < 16; ++d)
      *(fv4*)(op + d * 16) = acc2[d];
  }
}

// ---------------- host launch ----------------
extern "C" void kernel_launch(void* const* d_in, const int* in_sizes, int n_in,
                              void* d_out, int out_size, void* d_ws, size_t ws_size,
                              hipStream_t stream) {
  const float* x   = (const float*)d_in[0];
  const float* aug = (const float*)d_in[1];
  const float* wq  = (const float*)d_in[2];
  const float* wk  = (const float*)d_in[3];
  const float* wv  = (const float*)d_in[4];
  const float* wp  = (const float*)d_in[5];
  const float* bp  = (const float*)d_in[6];
  float* out = (float*)d_out;

  const size_t OFF_XA = 0;                       // 64 MiB: x_bf, later aug_bf
  const size_t OFF_WQ = 67108864;                // 32 MiB
  const size_t OFF_WK = OFF_WQ + 33554432;       // 32 MiB
  const size_t OFF_WV = OFF_WK + 33554432;       // 32 MiB (wp_bf overlays WQ+WK)
  const size_t OFF_Q  = OFF_WQ + 100663296;      // 64 MiB
  const size_t OFF_K  = OFF_Q + 67108864;        // 64 MiB
  const size_t OFF_VT = OFF_K + 67108864;        // 64 MiB
  const size_t OFF_EP = OFF_VT + 67108864;       // 128 MiB
  const size_t NEED   = OFF_EP + 134217728;      // 480 MiB total
  if (ws_size < NEED) return;

  char* ws = (char*)d_ws;
  unsigned short* x_bf   = (unsigned short*)(ws + OFF_XA);
  unsigned short* aug_bf = (unsigned short*)(ws + OFF_XA);
  unsigned short* wq_bf  = (unsigned short*)(ws + OFF_WQ);
  unsigned short* wk_bf  = (unsigned short*)(ws + OFF_WK);
  unsigned short* wv_bf  = (unsigned short*)(ws + OFF_WV);
  unsigned short* wp_bf  = (unsigned short*)(ws + OFF_WQ);
  unsigned short* q_bf   = (unsigned short*)(ws + OFF_Q);
  unsigned short* k_bf   = (unsigned short*)(ws + OFF_K);
  unsigned short* vt_bf  = (unsigned short*)(ws + OFF_VT);
  unsigned short* ep_bf  = (unsigned short*)(ws + OFF_EP);

  // phase A: convert x + QKV weights
  cvt_kernel<<<2048, 256, 0, stream>>>(x, x_bf, 33554432 / 4);
  cvt_kernel<<<2048, 256, 0, stream>>>(wq, wq_bf, 16777216 / 4);
  cvt_kernel<<<2048, 256, 0, stream>>>(wk, wk_bf, 16777216 / 4);
  cvt_kernel<<<2048, 256, 0, stream>>>(wv, wv_bf, 16777216 / 4);

  // Q = x @ Wq^T ; K = x @ Wk^T  (by=64, bx=16 -> grid 1024, bxsh=4)
  gemm128<0><<<1024, 256, 0, stream>>>(x_bf, wq_bf, q_bf, nullptr, 4096, 4096, 4);
  gemm128<0><<<1024, 256, 0, stream>>>(x_bf, wk_bf, k_bf, nullptr, 4096, 4096, 4);
  // Vt = Wv @ x^T  (by=32, bx=32 -> grid 1024, bxsh=5)
  gemm128<2><<<1024, 256, 0, stream>>>(wv_bf, x_bf, vt_bf, nullptr, 8192, 4096, 5);

  // phase B: x_bf dead -> reuse for aug; wq/wk dead -> reuse for wp
  cvt_kernel<<<2048, 256, 0, stream>>>(aug, aug_bf, 33554432 / 4);
  cvt_kernel<<<2048, 256, 0, stream>>>(wp, wp_bf, 33554432 / 4);
  // EP = Aug @ Wp^T + bp  (by=64, bx=32 -> grid 2048, bxsh=5)
  gemm128<1><<<2048, 256, 0, stream>>>(aug_bf, wp_bf, ep_bf, bp, 8192, 4096, 5);

  // fused attention
  attn_kernel<<<1024, 512, 0, stream>>>(q_bf, k_bf, vt_bf, ep_bf, out);
}

// Round 9
// 1721.347 us; speedup vs baseline: 1.1585x; 1.1585x over previous
//
#include <hip/hip_runtime.h>
#include <hip/hip_bf16.h>

typedef __attribute__((ext_vector_type(4))) float f32x4;
typedef __attribute__((ext_vector_type(8))) short s16x8;
typedef __attribute__((ext_vector_type(4))) short s16x4;
typedef __attribute__((ext_vector_type(8))) unsigned short u16x8;
typedef __attribute__((ext_vector_type(4))) unsigned short u16x4;
typedef __attribute__((ext_vector_type(4))) float fv4;

#define DEV static __device__ __forceinline__

DEV unsigned short f2bf(float f) {
  union { float f; unsigned u; } v; v.f = f;
  return (unsigned short)((v.u + 0x7fffu + ((v.u >> 16) & 1u)) >> 16);
}
DEV float bf2f(unsigned short u) {
  union { unsigned u; float f; } v; v.u = ((unsigned)u) << 16; return v.f;
}

typedef const __attribute__((address_space(1))) void* gas_t;
typedef __attribute__((address_space(3))) void* las_t;
DEV void load_lds16(const void* g, void* l) {
  __builtin_amdgcn_global_load_lds((gas_t)g, (las_t)l, 16, 0, 0);
}

// ---------------- fp32 -> bf16 convert ----------------
__global__ __launch_bounds__(256) void cvt_kernel(const float* __restrict__ in,
                                                  unsigned short* __restrict__ out,
                                                  int n4) {
  int i = blockIdx.x * 256 + threadIdx.x;
  int stride = gridDim.x * 256;
  for (; i < n4; i += stride) {
    fv4 v = *(const fv4*)(in + (size_t)i * 4);
    u16x4 o;
    o[0] = f2bf(v[0]); o[1] = f2bf(v[1]); o[2] = f2bf(v[2]); o[3] = f2bf(v[3]);
    *(u16x4*)(out + (size_t)i * 4) = o;
  }
}

// ---------------- 256x256 BT GEMM, BK=32, ring-4 LDS (R2 body) ------------
// C[m,n] = sum_k A[m,k]*B[n,k].
// R9 change is the BLOCK MAPPING ONLY: XCD-partitioned column sweep.
//   xcd = bid&7 (HW round-robin); j = bid>>3;
//   by = j & (nby-1); bx = xcd*(nbx/8) + (j >> bysh).
// All ~32 concurrent blocks on an XCD share ONE bx -> the 2 MB B-panel
// (256 cols x K=4096 bf16) lives in that XCD's private L2 and is fetched
// from HBM once; A panels stream through L3 (A fits entirely in 256 MB).
// Ideal HBM fetch ~130 MB/GEMM vs the 0.65-1.4 GB all previous rounds moved
// (R2-R8 walls == fetch_bytes/rate; MfmaUtil == 265us_MFMA_floor/wall).
// Swizzle (verified 0 conflicts): byte ^= ((row>>1)&3)<<4 on both sides.
// EPI: 0 = bf16 out (ldc=N), 1 = +bias[n] bf16, 2 = Vt mapping
//   addr = (n>>9)*2^21 + m*512 + (n&511)
template<int EPI>
__global__ __launch_bounds__(512, 2) void gemm256(const unsigned short* __restrict__ A,
                                                  const unsigned short* __restrict__ B,
                                                  unsigned short* __restrict__ C,
                                                  const float* __restrict__ bias,
                                                  int N, int K, int bysh, int bxpsh) {
  __shared__ unsigned short lds[4][2][8192]; // 4 bufs x (A,B) x 256x32 bf16 = 128 KiB
  const int t = threadIdx.x;
  const int lane = t & 63;
  const int w = t >> 6;
  const int wr = w >> 1, wc = w & 1;
  // R2 body used wr=w>>1(0..3),wc=w&1(0..1)? No: R2 had wr=w>>2? -- R2: wr=w>>2? It used
  // wr = w >> 2 (0..1), wc = w & 3 (0..3). Restore exactly:
  const int wr2 = w >> 2;  // 0..1
  const int wc2 = w & 3;   // 0..3
  const int r0 = lane & 15;
  const int g = lane >> 4; // 0..3

  const int bid = blockIdx.x;
  const int xcd = bid & 7;
  const int j = bid >> 3;
  const int by = j & ((1 << bysh) - 1);
  const int bx = (xcd << bxpsh) + (j >> bysh);
  const long brow = (long)by * 256;
  const long bcol = (long)bx * 256;

  // staging: thread t loads 16B; LDS linear pos p = t*16 (+8192 for row+128)
  const int srow = t >> 2;                            // 0..127
  const int scol = ((t & 3) ^ ((t >> 3) & 3)) * 8;    // elems, pre-swizzled
  const unsigned short* As = A + (brow + srow) * (long)K + scol;
  const unsigned short* Bs = B + (bcol + srow) * (long)K + scol;
  const int d0 = t * 8; // elems

#define STAGE(kt, bufi)                                                 \
  do {                                                                  \
    const long k0_ = (long)(kt) << 5;                                   \
    load_lds16(As + k0_,                 &lds[bufi][0][d0]);            \
    load_lds16(As + 128 * (long)K + k0_, &lds[bufi][0][d0 + 4096]);     \
    load_lds16(Bs + k0_,                 &lds[bufi][1][d0]);            \
    load_lds16(Bs + 128 * (long)K + k0_, &lds[bufi][1][d0 + 4096]);     \
  } while (0)

  f32x4 acc[8][4] = {};
  const int NT = K >> 5;

  // prologue: 3 tiles in flight, drain tile 0 (12 outstanding -> keep 8)
  STAGE(0, 0); STAGE(1, 1); STAGE(2, 2);
  asm volatile("s_waitcnt vmcnt(8)" ::: "memory");
  __builtin_amdgcn_s_barrier();
  __builtin_amdgcn_sched_barrier(0);

  // swizzled k-column offset: constant per lane ((row>>1)&3 == (r0>>1)&3)
  const int cswz = (g ^ ((r0 >> 1) & 3)) * 8; // elems
  const int arow = wr2 * 128 + r0;
  const int brw = wc2 * 64 + r0;

  for (int kt = 0; kt < NT; ++kt) {
    const unsigned short* lA = &lds[kt & 3][0][0];
    const unsigned short* lB = &lds[kt & 3][1][0];
    if (kt + 3 < NT) STAGE(kt + 3, (kt + 3) & 3);
    s16x8 av[8], bv[4];
#pragma unroll
    for (int m = 0; m < 8; ++m)
      av[m] = *(const s16x8*)&lA[(arow + m * 16) * 32 + cswz];
#pragma unroll
    for (int n = 0; n < 4; ++n)
      bv[n] = *(const s16x8*)&lB[(brw + n * 16) * 32 + cswz];
    __builtin_amdgcn_s_setprio(1);
#pragma unroll
    for (int m = 0; m < 8; ++m)
#pragma unroll
      for (int n = 0; n < 4; ++n)
        acc[m][n] = __builtin_amdgcn_mfma_f32_16x16x32_bf16(av[m], bv[n], acc[m][n], 0, 0, 0);
    __builtin_amdgcn_s_setprio(0);
    // boundary: tile kt+1 must be drained; tiles kt+2, kt+3 may stay in flight
    const int rem = NT - 1 - kt;
    if (rem >= 3)      asm volatile("s_waitcnt vmcnt(8)" ::: "memory");
    else if (rem == 2) asm volatile("s_waitcnt vmcnt(4)" ::: "memory");
    else if (rem == 1) asm volatile("s_waitcnt vmcnt(0)" ::: "memory");
    __builtin_amdgcn_s_barrier();
    __builtin_amdgcn_sched_barrier(0);
  }
#undef STAGE

  const int g4 = g * 4;
#pragma unroll
  for (int m = 0; m < 8; ++m) {
#pragma unroll
    for (int n = 0; n < 4; ++n) {
      f32x4 v = acc[m][n];
      long col = bcol + wc2 * 64 + n * 16 + r0;
#pragma unroll
      for (int r = 0; r < 4; ++r) {
        long row = brow + wr2 * 128 + m * 16 + g4 + r;
        float val = v[r];
        if (EPI == 1) val += bias[col];
        if (EPI == 2) {
          long addr = ((col >> 9) << 21) + (row << 9) + (col & 511);
          C[addr] = f2bf(val);
        } else {
          C[row * (long)N + col] = f2bf(val);
        }
      }
    }
  }
}

// ---------------- fused attention ----------------
// grid: 1024 = B(16) * NH(16) * 4 q-tiles ; block: 512 (8 waves x 16 q-rows)
__global__ __launch_bounds__(512, 2) void attn_kernel(const unsigned short* __restrict__ Q,
                                                      const unsigned short* __restrict__ K,
                                                      const unsigned short* __restrict__ V,
                                                      const unsigned short* __restrict__ EP,
                                                      float* __restrict__ out) {
  __shared__ unsigned short lds[256 * 136]; // also used as [128][264]
  const int t = threadIdx.x;
  const int lane = t & 63;
  const int w = t >> 6;
  const int bid = blockIdx.x;
  const int qt = bid & 3;
  const int h = (bid >> 2) & 15;
  const int b = bid >> 6;
  const int r0 = lane & 15;
  const int g = lane >> 4;

  const int qrow = qt * 128 + w * 16;

  s16x8 qf[8];
  {
    const unsigned short* qp = Q + ((size_t)(b * 512 + qrow + r0)) * 4096 + h * 256 + g * 8;
#pragma unroll
    for (int s = 0; s < 8; ++s) qf[s] = *(const s16x8*)(qp + s * 32);
  }

  f32x4 st[32];
#pragma unroll
  for (int f = 0; f < 32; ++f) st[f] = f32x4{0.f, 0.f, 0.f, 0.f};

#pragma unroll
  for (int kc = 0; kc < 4; ++kc) {
    {
      const unsigned short* kp = K + ((size_t)(b * 512 + kc * 128)) * 4096 + h * 256;
#pragma unroll
      for (int u = 0; u < 8; ++u) {
        int fidx = u * 4096 + t * 8;
        int row = fidx >> 8, c = fidx & 255;
        u16x8 v = *(const u16x8*)(kp + (size_t)row * 4096 + c);
        *(u16x8*)&lds[row * 264 + c] = v;
      }
    }
    __syncthreads();
#pragma unroll
    for (int mf = 0; mf < 8; ++mf) {
      const unsigned short* lk = &lds[(mf * 16 + r0) * 264 + g * 8];
#pragma unroll
      for (int s = 0; s < 8; ++s) {
        s16x8 af = *(const s16x8*)(lk + s * 32);
        st[kc * 8 + mf] = __builtin_amdgcn_mfma_f32_16x16x32_bf16(af, qf[s], st[kc * 8 + mf], 0, 0, 0);
      }
    }
    __syncthreads();
  }

  {
    const unsigned short* ep = EP + ((size_t)(b * 512 + qrow + r0)) * 8192 + h * 512 + g * 4;
#pragma unroll
    for (int f = 0; f < 32; ++f) {
      u16x4 e = *(const u16x4*)(ep + f * 16);
#pragma unroll
      for (int r = 0; r < 4; ++r)
        st[f][r] = st[f][r] * 0.0625f + bf2f(e[r]);
    }
  }

  float mx = -1e30f;
#pragma unroll
  for (int f = 0; f < 32; ++f)
    mx = fmaxf(mx, fmaxf(fmaxf(st[f][0], st[f][1]), fmaxf(st[f][2], st[f][3])));
  mx = fmaxf(mx, __shfl_xor(mx, 16, 64));
  mx = fmaxf(mx, __shfl_xor(mx, 32, 64));
  float sum = 0.f;
#pragma unroll
  for (int f = 0; f < 32; ++f) {
#pragma unroll
    for (int r = 0; r < 4; ++r) {
      float e = __expf(st[f][r] - mx);
      st[f][r] = e;
      sum += e;
    }
  }
  sum += __shfl_xor(sum, 16, 64);
  sum += __shfl_xor(sum, 32, 64);
  const float rinv = 1.0f / sum;

  s16x8 pb[16];
#pragma unroll
  for (int p = 0; p < 16; ++p) {
    s16x8 v;
#pragma unroll
    for (int j = 0; j < 4; ++j) {
      v[j] = (short)f2bf(st[2 * p][j] * rinv);
      v[j + 4] = (short)f2bf(st[2 * p + 1][j] * rinv);
    }
    pb[p] = v;
  }

  f32x4 acc2[16];
#pragma unroll
  for (int d = 0; d < 16; ++d) acc2[d] = f32x4{0.f, 0.f, 0.f, 0.f};

#pragma unroll
  for (int kc = 0; kc < 4; ++kc) {
    {
      const unsigned short* vp = V + ((size_t)(b * 16 + h)) * 131072 + kc * 128;
#pragma unroll
      for (int u = 0; u < 8; ++u) {
        int fidx = u * 4096 + t * 8;
        int row = fidx >> 7, c = fidx & 127;
        u16x8 vv = *(const u16x8*)(vp + (size_t)row * 512 + c);
        *(u16x8*)&lds[row * 136 + c] = vv;
      }
    }
    __syncthreads();
#pragma unroll
    for (int d = 0; d < 16; ++d) {
      const unsigned short* lv = &lds[(d * 16 + r0) * 136 + g * 4];
#pragma unroll
      for (int p = 0; p < 4; ++p) {
        s16x4 a0 = *(const s16x4*)(lv + p * 32);
        s16x4 a1 = *(const s16x4*)(lv + p * 32 + 16);
        s16x8 av;
        av[0] = a0[0]; av[1] = a0[1]; av[2] = a0[2]; av[3] = a0[3];
        av[4] = a1[0]; av[5] = a1[1]; av[6] = a1[2]; av[7] = a1[3];
        acc2[d] = __builtin_amdgcn_mfma_f32_16x16x32_bf16(av, pb[kc * 4 + p], acc2[d], 0, 0, 0);
      }
    }
    __syncthreads();
  }

  {
    float* op = out + ((size_t)(b * 512 + qrow + r0)) * 4096 + h * 256 + g * 4;
#pragma unroll
    for (int d = 0; d < 16; ++d)
      *(fv4*)(op + d * 16) = acc2[d];
  }
}

// ---------------- host launch ----------------
extern "C" void kernel_launch(void* const* d_in, const int* in_sizes, int n_in,
                              void* d_out, int out_size, void* d_ws, size_t ws_size,
                              hipStream_t stream) {
  const float* x   = (const float*)d_in[0];
  const float* aug = (const float*)d_in[1];
  const float* wq  = (const float*)d_in[2];
  const float* wk  = (const float*)d_in[3];
  const float* wv  = (const float*)d_in[4];
  const float* wp  = (const float*)d_in[5];
  const float* bp  = (const float*)d_in[6];
  float* out = (float*)d_out;

  const size_t OFF_XA = 0;                       // 64 MiB: x_bf, later aug_bf
  const size_t OFF_WQ = 67108864;                // 32 MiB
  const size_t OFF_WK = OFF_WQ + 33554432;       // 32 MiB
  const size_t OFF_WV = OFF_WK + 33554432;       // 32 MiB (wp_bf overlays WQ+WK)
  const size_t OFF_Q  = OFF_WQ + 100663296;      // 64 MiB
  const size_t OFF_K  = OFF_Q + 67108864;        // 64 MiB
  const size_t OFF_VT = OFF_K + 67108864;        // 64 MiB
  const size_t OFF_EP = OFF_VT + 67108864;       // 128 MiB
  const size_t NEED   = OFF_EP + 134217728;      // 480 MiB total
  if (ws_size < NEED) return;

  char* ws = (char*)d_ws;
  unsigned short* x_bf   = (unsigned short*)(ws + OFF_XA);
  unsigned short* aug_bf = (unsigned short*)(ws + OFF_XA);
  unsigned short* wq_bf  = (unsigned short*)(ws + OFF_WQ);
  unsigned short* wk_bf  = (unsigned short*)(ws + OFF_WK);
  unsigned short* wv_bf  = (unsigned short*)(ws + OFF_WV);
  unsigned short* wp_bf  = (unsigned short*)(ws + OFF_WQ);
  unsigned short* q_bf   = (unsigned short*)(ws + OFF_Q);
  unsigned short* k_bf   = (unsigned short*)(ws + OFF_K);
  unsigned short* vt_bf  = (unsigned short*)(ws + OFF_VT);
  unsigned short* ep_bf  = (unsigned short*)(ws + OFF_EP);

  // phase A: convert x + QKV weights
  cvt_kernel<<<2048, 256, 0, stream>>>(x, x_bf, 33554432 / 4);
  cvt_kernel<<<2048, 256, 0, stream>>>(wq, wq_bf, 16777216 / 4);
  cvt_kernel<<<2048, 256, 0, stream>>>(wk, wk_bf, 16777216 / 4);
  cvt_kernel<<<2048, 256, 0, stream>>>(wv, wv_bf, 16777216 / 4);

  // Q = x @ Wq^T ; K = x @ Wk^T  (nby=32 bysh=5, nbx=16 -> bxpsh=1, grid 512)
  gemm256<0><<<512, 512, 0, stream>>>(x_bf, wq_bf, q_bf, nullptr, 4096, 4096, 5, 1);
  gemm256<0><<<512, 512, 0, stream>>>(x_bf, wk_bf, k_bf, nullptr, 4096, 4096, 5, 1);
  // Vt = Wv @ x^T  (nby=16 bysh=4, nbx=32 -> bxpsh=2, grid 512)
  gemm256<2><<<512, 512, 0, stream>>>(wv_bf, x_bf, vt_bf, nullptr, 8192, 4096, 4, 2);

  // phase B: x_bf dead -> reuse for aug; wq/wk dead -> reuse for wp
  cvt_kernel<<<2048, 256, 0, stream>>>(aug, aug_bf, 33554432 / 4);
  cvt_kernel<<<2048, 256, 0, stream>>>(wp, wp_bf, 33554432 / 4);
  // EP = Aug @ Wp^T + bp  (nby=32 bysh=5, nbx=32 -> bxpsh=2, grid 1024)
  gemm256<1><<<1024, 512, 0, stream>>>(aug_bf, wp_bf, ep_bf, bp, 8192, 4096, 5, 2);

  // fused attention
  attn_kernel<<<1024, 512, 0, stream>>>(q_bf, k_bf, vt_bf, ep_bf, out);
}